// Round 3
// baseline (136.114 us; speedup 1.0000x reference)
//
#include <hip/hip_runtime.h>

#define B_SZ 16384
#define D_SZ 256
#define C_SZ 2000
#define C_PAD 2048
#define MARGIN_F 1.0f

typedef __bf16 bf16x8 __attribute__((ext_vector_type(8)));
typedef __bf16 bf16x4 __attribute__((ext_vector_type(4)));
typedef float floatx16 __attribute__((ext_vector_type(16)));

__device__ inline void gld_lds16(const void* g, void* l) {
  __builtin_amdgcn_global_load_lds(
      (const __attribute__((address_space(1))) void*)g,
      (__attribute__((address_space(3))) void*)l, 16, 0, 0);
}

// ---- sig (D x C) fp32 -> sigT (C_PAD x D) bf16 via LDS transpose ----
// one block per 64 classes; conflict-free padded LDS tile
__global__ __launch_bounds__(256) void convert_sigT_kernel(
    const float* __restrict__ sig, __bf16* __restrict__ sigT) {
  __shared__ __bf16 tr[64][D_SZ + 2];
  int tid = threadIdx.x;
  int c0 = blockIdx.x * 64;
#pragma unroll
  for (int d0 = 0; d0 < D_SZ; d0 += 4) {
    int d = d0 + (tid >> 6);
    int c = c0 + (tid & 63);
    float v = (c < C_SZ) ? sig[(size_t)d * C_SZ + c] : 0.f;
    tr[tid & 63][d] = (__bf16)v;
  }
  __syncthreads();
#pragma unroll
  for (int t = 0; t < 8; t++) {
    int q = t * 256 + tid;        // 2048 chunks of 8 elems
    int c = q >> 5;
    int d0 = (q & 31) * 8;
    bf16x8 o;
#pragma unroll
    for (int i = 0; i < 8; i++) o[i] = tr[c][d0 + i];
    *(bf16x8*)(sigT + (size_t)(c0 + c) * D_SZ + d0) = o;
  }
}

// ---- fused: pred fp32 -> bf16, and gt[b] = dot(pred[b], sigT[label[b]]) ----
// one wave per row
__global__ __launch_bounds__(256) void pred_gt_kernel(
    const float* __restrict__ pred, const __bf16* __restrict__ sigT,
    const int* __restrict__ label, __bf16* __restrict__ predb,
    float* __restrict__ gt) {
  int row = (blockIdx.x * 256 + threadIdx.x) >> 6;
  int lane = threadIdx.x & 63;
  float4 p = *(const float4*)(pred + (size_t)row * D_SZ + lane * 4);
  bf16x4 pb;
  pb[0] = (__bf16)p.x; pb[1] = (__bf16)p.y; pb[2] = (__bf16)p.z; pb[3] = (__bf16)p.w;
  *(bf16x4*)(predb + (size_t)row * D_SZ + lane * 4) = pb;
  int lbl = label[row];
  bf16x4 s = *(const bf16x4*)(sigT + (size_t)lbl * D_SZ + lane * 4);
  float sum = 0.f;
#pragma unroll
  for (int i = 0; i < 4; i++) sum += (float)pb[i] * (float)s[i];
#pragma unroll
  for (int off = 32; off > 0; off >>= 1) sum += __shfl_down(sum, off, 64);
  if (lane == 0) gt[row] = sum;
}

// ---- fused MFMA GEMM + hinge + reduce ----
// block tile 128(M) x 256(N), BK=64, 4 waves in 2x2, each wave 64x128
// via 2x4 tiles of mfma_f32_32x32x16_bf16 (42.7 FLOP per LDS byte)
// LDS layout As2[kc][r][8] / Bs2[kc][c][8]: frag reads are lane-consecutive
// 16B chunks -> conflict-free; global_load_lds dest stays contiguous.
__global__ __launch_bounds__(256, 2) void mfma_fused_kernel(
    const __bf16* __restrict__ A,   // predb [B_SZ][D_SZ]
    const __bf16* __restrict__ Bt,  // sigT  [C_PAD][D_SZ]
    const int* __restrict__ label, const float* __restrict__ gt,
    float* __restrict__ out) {
  __shared__ __bf16 As2[8 * 128 * 8];   // 16 KB: [kc][r 0..127][8]
  __shared__ __bf16 Bs2[8 * 256 * 8];   // 32 KB: [kc][c 0..255][8]
  __shared__ float gtS[128];
  __shared__ int lblS[128];
  __shared__ float red[4];

  int tid = threadIdx.x;
  int lane = tid & 63;
  int w = tid >> 6;
  int wy = w >> 1, wx = w & 1;   // wave covers rows wy*64.., cols wx*128..
  int lm32 = lane & 31, kh = lane >> 5;
  int tileRow = (int)(blockIdx.x >> 3) * 128;   // col-tile fastest: 8 share A via L2
  int tileCol = (int)(blockIdx.x & 7) * 256;

  if (tid < 128) {
    gtS[tid] = gt[tileRow + tid];
    lblS[tid] = label[tileRow + tid];
  }

  floatx16 acc[2][4] = {};

  for (int kk = 0; kk < D_SZ; kk += 64) {
    // stage A: 1024 chunks of 16B, 4 instr/wave
#pragma unroll
    for (int t = 0; t < 4; t++) {
      int q0 = w * 256 + t * 64;
      int q = q0 + lane;
      int kc = q >> 7, r = q & 127;
      gld_lds16(A + (size_t)(tileRow + r) * D_SZ + kk + kc * 8,
                (void*)(As2 + q0 * 8));
    }
    // stage B: 2048 chunks, 8 instr/wave
#pragma unroll
    for (int t = 0; t < 8; t++) {
      int q0 = w * 512 + t * 64;
      int q = q0 + lane;
      int kc = q >> 8, c = q & 255;
      gld_lds16(Bt + (size_t)(tileCol + c) * D_SZ + kk + kc * 8,
                (void*)(Bs2 + q0 * 8));
    }
    __syncthreads();

#pragma unroll
    for (int s = 0; s < 4; s++) {   // k-steps of 16
      bf16x8 a[2], b[4];
#pragma unroll
      for (int i = 0; i < 2; i++)
        a[i] = *(const bf16x8*)(As2 + ((s * 2 + kh) * 128 + wy * 64 + i * 32 + lm32) * 8);
#pragma unroll
      for (int j = 0; j < 4; j++)
        b[j] = *(const bf16x8*)(Bs2 + ((s * 2 + kh) * 256 + wx * 128 + j * 32 + lm32) * 8);
#pragma unroll
      for (int i = 0; i < 2; i++)
#pragma unroll
        for (int j = 0; j < 4; j++)
          acc[i][j] = __builtin_amdgcn_mfma_f32_32x32x16_bf16(a[i], b[j], acc[i][j], 0, 0, 0);
    }
    __syncthreads();
  }

  // epilogue: C/D layout col=lane&31, row=(reg&3)+8*(reg>>2)+4*(lane>>5)
  float sum = 0.f;
#pragma unroll
  for (int i = 0; i < 2; i++) {
#pragma unroll
    for (int reg = 0; reg < 16; reg++) {
      int lrow = wy * 64 + i * 32 + (reg & 3) + 8 * (reg >> 2) + 4 * kh;
      float g = gtS[lrow];
      int lbl = lblS[lrow];
#pragma unroll
      for (int j = 0; j < 4; j++) {
        int col = tileCol + wx * 128 + j * 32 + lm32;
        if (col < C_SZ && col != lbl)
          sum += fmaxf(MARGIN_F + acc[i][j][reg] - g, 0.f);
      }
    }
  }
#pragma unroll
  for (int off = 32; off > 0; off >>= 1) sum += __shfl_down(sum, off, 64);
  if (lane == 0) red[w] = sum;
  __syncthreads();
  if (tid == 0) atomicAdd(out, red[0] + red[1] + red[2] + red[3]);
}

extern "C" void kernel_launch(void* const* d_in, const int* in_sizes, int n_in,
                              void* d_out, int out_size, void* d_ws, size_t ws_size,
                              hipStream_t stream) {
  const float* pred  = (const float*)d_in[0];   // (B, D) fp32
  const int*   label = (const int*)d_in[1];     // (B,) int
  // d_in[2] = train_classes = arange(C), unused
  const float* sig   = (const float*)d_in[3];   // (D, C) fp32
  float* out = (float*)d_out;

  float*  gt    = (float*)d_ws;                                   // 64 KB
  __bf16* predb = (__bf16*)((char*)d_ws + (64 << 10));            // 8 MB
  __bf16* sigT  = (__bf16*)((char*)d_ws + (64 << 10) + (8 << 20));// 1 MB

  hipMemsetAsync(out, 0, sizeof(float), stream);
  convert_sigT_kernel<<<C_PAD / 64, 256, 0, stream>>>(sig, sigT);
  pred_gt_kernel<<<B_SZ / 4, 256, 0, stream>>>(pred, sigT, label, predb, gt);
  mfma_fused_kernel<<<(B_SZ / 128) * (C_PAD / 256), 256, 0, stream>>>(
      predb, sigT, label, gt, out);
}